// Round 12
// baseline (23.961 us; speedup 1.0000x reference)
//
#include <hip/hip_runtime.h>
#include <math.h>

#define NB 32
#define NPTS 200000
#define N4 (NPTS / 4)
#define THREADS 512
#define BPB 32                    // grid = NB*BPB = 1024 blocks; CHUNK = 1563
#define IMG_W_C 1280.0f
#define IMG_H_C 384.0f

#define FINL __device__ __forceinline__

typedef float v2f __attribute__((ext_vector_type(2)));

FINL v2f v2_fma(v2f a, v2f b, v2f c) { return __builtin_elementwise_fma(a, b, c); }
FINL v2f v2_splat(float s) { v2f r; r.x = s; r.y = s; return r; }

// Build M = K @ [R|t] (3x4, row-major). Per-thread; block-uniform inputs let the
// compiler home M in SGPRs (matrices become scalar operands to v_fma).
FINL void make_mat(const float* __restrict__ q4, const float* __restrict__ t3,
                   const float* __restrict__ K9, float* M) {
    float qw = q4[0], qx = q4[1], qy = q4[2], qz = q4[3];
    float inv = __builtin_amdgcn_rsqf(qw * qw + qx * qx + qy * qy + qz * qz);
    qw *= inv; qx *= inv; qy *= inv; qz *= inv;
    float R[9];
    R[0] = 1.f - 2.f * (qy * qy + qz * qz); R[1] = 2.f * (qx * qy - qz * qw); R[2] = 2.f * (qx * qz + qy * qw);
    R[3] = 2.f * (qx * qy + qz * qw); R[4] = 1.f - 2.f * (qx * qx + qz * qz); R[5] = 2.f * (qy * qz - qx * qw);
    R[6] = 2.f * (qx * qz - qy * qw); R[7] = 2.f * (qy * qz + qx * qw); R[8] = 1.f - 2.f * (qx * qx + qy * qy);
    #pragma unroll
    for (int i = 0; i < 3; i++) {
        float k0 = K9[i * 3 + 0], k1 = K9[i * 3 + 1], k2 = K9[i * 3 + 2];
        M[i * 4 + 0] = k0 * R[0] + k1 * R[3] + k2 * R[6];
        M[i * 4 + 1] = k0 * R[1] + k1 * R[4] + k2 * R[7];
        M[i * 4 + 2] = k0 * R[2] + k1 * R[5] + k2 * R[8];
        M[i * 4 + 3] = k0 * t3[0] + k1 * t3[1] + k2 * t3[2];
    }
}

FINL float pose_loss(int b, const float* __restrict__ tgt_t, const float* __restrict__ tgt_r,
                     const float* __restrict__ err_t, const float* __restrict__ err_r) {
    float lt = 0.f;
    #pragma unroll
    for (int c = 0; c < 3; c++) {
        float d = err_t[b * 3 + c] - tgt_t[b * 3 + c];
        float ad = fabsf(d);
        lt += (ad < 1.0f) ? 0.5f * d * d : (ad - 0.5f);
    }
    float qw = err_r[b * 4], qx = err_r[b * 4 + 1], qy = err_r[b * 4 + 2], qz = err_r[b * 4 + 3];
    float rn = 1.0f / sqrtf(qw * qw + qx * qx + qy * qy + qz * qz);
    qw *= rn; qx *= rn; qy *= rn; qz *= rn;
    float rw_ = tgt_r[b * 4], rx = tgt_r[b * 4 + 1], ry = tgt_r[b * 4 + 2], rz = tgt_r[b * 4 + 3];
    float rn2 = 1.0f / sqrtf(rw_ * rw_ + rx * rx + ry * ry + rz * rz);
    rw_ *= rn2; rx = -rx * rn2; ry = -ry * rn2; rz = -rz * rn2;  // r^-1
    float dw = qw * rw_ - qx * rx - qy * ry - qz * rz;
    float dx = qw * rx + qx * rw_ + qy * rz - qz * ry;
    float dy = qw * ry - qx * rz + qy * rw_ + qz * rx;
    float dz = qw * rz + qx * ry - qy * rx + qz * rw_;
    float lr = 2.0f * atan2f(sqrtf(dx * dx + dy * dy + dz * dz), fabsf(dw));
    return lr + lt;
}

// Pair-processing contributor. mg/mp rows 0,1 are PRE-FOLDED: row0' = row0-cx*row2,
// row1' = row1-cy*row2 — so u = g0'/g2 = Fg-cx (dx directly), dF = u_g-u_p (cx
// cancels), bounds Fg in (0,W) become u in (-cx, W-cx). FMA/mul/add run as
// float2 vectors -> v_pk_*_f32 (VOP3P); min/max/cmp/trans have no packed f32
// form and stay scalar per element.
FINL void pair_contrib(const float* __restrict__ mg, const float* __restrict__ mp,
                       float cx, float cy, float wcx, float wcy,
                       v2f X, v2f Y, v2f Z, v2f& SW, v2f& SE) {
    v2f G0 = v2_fma(v2_splat(mg[0]), X, v2_fma(v2_splat(mg[1]), Y, v2_fma(v2_splat(mg[2]), Z, v2_splat(mg[3]))));
    v2f G1 = v2_fma(v2_splat(mg[4]), X, v2_fma(v2_splat(mg[5]), Y, v2_fma(v2_splat(mg[6]), Z, v2_splat(mg[7]))));
    v2f G2 = v2_fma(v2_splat(mg[8]), X, v2_fma(v2_splat(mg[9]), Y, v2_fma(v2_splat(mg[10]), Z, v2_splat(mg[11]))));
    v2f P0 = v2_fma(v2_splat(mp[0]), X, v2_fma(v2_splat(mp[1]), Y, v2_fma(v2_splat(mp[2]), Z, v2_splat(mp[3]))));
    v2f P1 = v2_fma(v2_splat(mp[4]), X, v2_fma(v2_splat(mp[5]), Y, v2_fma(v2_splat(mp[6]), Z, v2_splat(mp[7]))));
    v2f P2 = v2_fma(v2_splat(mp[8]), X, v2_fma(v2_splat(mp[9]), Y, v2_fma(v2_splat(mp[10]), Z, v2_splat(mp[11]))));

    v2f IG, IP;
    IG.x = __builtin_amdgcn_rcpf(G2.x); IG.y = __builtin_amdgcn_rcpf(G2.y);
    IP.x = __builtin_amdgcn_rcpf(P2.x); IP.y = __builtin_amdgcn_rcpf(P2.y);

    v2f UG = G0 * IG, VG = G1 * IG;    // = (Fg-cx, Sg-cy)
    v2f UP = P0 * IP, VP = P1 * IP;    // = (F1-cx, S1-cy)

    v2f DF = UG - UP, DS = VG - VP;    // cx/cy cancel exactly in the in-bounds case

    v2f DFm, DSm;
    #pragma unroll
    for (int e = 0; e < 2; e++) {
        float ug = UG[e], up = UP[e], vg = VG[e], vp = VP[e];
        float mF = fminf(fminf(ug, up) + cx, wcx - fmaxf(ug, up));
        float mS = fminf(fminf(vg, vp) + cy, wcy - fmaxf(vg, vp));
        DFm[e] = (mF > 0.f) ? DF[e] : 0.f;
        DSm[e] = (mS > 0.f) ? DS[e] : 0.f;
    }

    v2f T  = v2_fma(UG, UG, VG * VG);      // dx^2+dy^2
    v2f E2 = v2_fma(DFm, DFm, DSm * DSm);
    v2f RW, E;
    RW.x = __builtin_amdgcn_rsqf(T.x); RW.y = __builtin_amdgcn_rsqf(T.y);
    E.x = __builtin_amdgcn_sqrtf(E2.x); E.y = __builtin_amdgcn_sqrtf(E2.y);

    SW = SW + RW;
    SE = v2_fma(E, RW, SE);
}

// Balanced block-chunked partition (R10): block cb owns float4s
// [cb*CHUNK, min(cb*CHUNK+CHUNK, N4)); coalesced (lane i at base+tid).
__global__ __launch_bounds__(THREADS, 4)
void pc_partial(const float* __restrict__ pc,
                const float* __restrict__ tgt_t, const float* __restrict__ tgt_r,
                const float* __restrict__ err_t, const float* __restrict__ err_r,
                const float* __restrict__ cam,
                float2* __restrict__ partial /* [NB * BPB] interleaved */) {
    const int b  = blockIdx.x / BPB;
    const int cb = blockIdx.x % BPB;

    float mg[12], mp[12];
    make_mat(tgt_r + b * 4, tgt_t + b * 3, cam + b * 9, mg);
    make_mat(err_r + b * 4, err_t + b * 3, cam + b * 9, mp);
    const float cx = cam[b * 9 + 2];
    const float cy = cam[b * 9 + 5];
    const float wcx = IMG_W_C - cx, wcy = IMG_H_C - cy;
    // Fold principal point into rows 0,1: row0' = row0 - cx*row2, row1' = row1 - cy*row2.
    #pragma unroll
    for (int j = 0; j < 4; j++) {
        mg[j]     = fmaf(-cx, mg[8 + j], mg[j]);
        mg[4 + j] = fmaf(-cy, mg[8 + j], mg[4 + j]);
        mp[j]     = fmaf(-cx, mp[8 + j], mp[j]);
        mp[4 + j] = fmaf(-cy, mp[8 + j], mp[4 + j]);
    }

    // point_clouds (B, 4, N): planes x,y,z contiguous in n; ones-plane skipped.
    const float4* __restrict__ Xp = (const float4*)(pc + (size_t)b * 4 * NPTS);
    const float4* __restrict__ Yp = (const float4*)(pc + (size_t)b * 4 * NPTS + NPTS);
    const float4* __restrict__ Zp = (const float4*)(pc + (size_t)b * 4 * NPTS + 2 * NPTS);

    v2f SW = v2_splat(0.f), SE = v2_splat(0.f);
    constexpr int CHUNK = (N4 + BPB - 1) / BPB;
    const int base = cb * CHUNK;
    const int lim  = (base + CHUNK < N4) ? (base + CHUNK) : N4;

    for (int i = base + (int)threadIdx.x; i < lim; i += THREADS) {
        float4 xv = Xp[i], yv = Yp[i], zv = Zp[i];
        v2f Xa, Ya, Za, Xb, Yb, Zb;
        Xa.x = xv.x; Xa.y = xv.y;  Ya.x = yv.x; Ya.y = yv.y;  Za.x = zv.x; Za.y = zv.y;
        Xb.x = xv.z; Xb.y = xv.w;  Yb.x = yv.z; Yb.y = yv.w;  Zb.x = zv.z; Zb.y = zv.w;
        pair_contrib(mg, mp, cx, cy, wcx, wcy, Xa, Ya, Za, SW, SE);
        pair_contrib(mg, mp, cx, cy, wcx, wcy, Xb, Yb, Zb, SW, SE);
    }

    float sum_w = SW.x + SW.y;
    float sum_e = SE.x + SE.y;

    #pragma unroll
    for (int off = 32; off > 0; off >>= 1) {
        sum_w += __shfl_down(sum_w, off);
        sum_e += __shfl_down(sum_e, off);
    }
    __shared__ float red[2][THREADS / 64];
    const int wave = threadIdx.x >> 6;
    if ((threadIdx.x & 63) == 0) { red[0][wave] = sum_w; red[1][wave] = sum_e; }
    __syncthreads();
    if (threadIdx.x == 0) {
        float sw = 0.f, se = 0.f;
        #pragma unroll
        for (int k = 0; k < THREADS / 64; k++) { sw += red[0][k]; se += red[1][k]; }
        partial[blockIdx.x] = make_float2(sw, se);
    }
}

// Parallel finalize (R9, verified ~1.5us): one block, 32 threads per batch,
// coalesced float2 loads of the partials.
__global__ __launch_bounds__(1024)
void finalize_par(const float* __restrict__ tgt_t, const float* __restrict__ tgt_r,
                  const float* __restrict__ err_t, const float* __restrict__ err_r,
                  const float2* __restrict__ partial, float* __restrict__ out) {
    const int tid = threadIdx.x;          // 0..1023
    const int b = tid >> 5;               // 32 threads per batch
    const int k = tid & 31;

    float sw = 0.f, se = 0.f;
    #pragma unroll
    for (int j = k; j < BPB; j += 32) {   // BPB=32: 1 coalesced float2 load
        float2 p = partial[b * BPB + j];
        sw += p.x; se += p.y;
    }
    #pragma unroll
    for (int off = 16; off > 0; off >>= 1) {
        sw += __shfl_xor(sw, off);
        se += __shfl_xor(se, off);
    }

    __shared__ float sval[NB];
    if (k == 0) {
        float pc_b = se / fmaxf(sw, 5.0f) * (1.0f / NPTS);
        sval[b] = 0.5f * pose_loss(b, tgt_t, tgt_r, err_t, err_r) + 0.5f * pc_b;
    }
    __syncthreads();
    if (tid < 64) {
        float v = (tid < NB) ? sval[tid] : 0.f;
        #pragma unroll
        for (int off = 32; off > 0; off >>= 1) v += __shfl_down(v, off);
        if (tid == 0) out[0] = v * (1.0f / NB);
    }
}

extern "C" void kernel_launch(void* const* d_in, const int* in_sizes, int n_in,
                              void* d_out, int out_size, void* d_ws, size_t ws_size,
                              hipStream_t stream) {
    const float* pc    = (const float*)d_in[0];
    const float* tgt_t = (const float*)d_in[1];
    const float* tgt_r = (const float*)d_in[2];
    const float* err_t = (const float*)d_in[3];
    const float* err_r = (const float*)d_in[4];
    const float* cam   = (const float*)d_in[5];
    float2* partial = (float2*)d_ws;      // NB*BPB float2 = 8 KB
    float* out = (float*)d_out;

    pc_partial<<<NB * BPB, THREADS, 0, stream>>>(pc, tgt_t, tgt_r, err_t, err_r, cam, partial);
    finalize_par<<<1, 1024, 0, stream>>>(tgt_t, tgt_r, err_t, err_r, partial, out);
}